// Round 1
// baseline (511.022 us; speedup 1.0000x reference)
//
#include <hip/hip_runtime.h>

#define NBATCH 2048
#define CIN 512
#define NTOK 64
#define NHEAD 4
#define NINTER 256

typedef __attribute__((ext_vector_type(8))) short short8;
typedef __attribute__((ext_vector_type(4))) float f32x4;
typedef __attribute__((ext_vector_type(4))) unsigned short us4;

__device__ __forceinline__ unsigned short f2bf(float f) {
    unsigned int u = __float_as_uint(f);
    u += 0x7FFFu + ((u >> 16) & 1u);
    return (unsigned short)(u >> 16);
}
__device__ __forceinline__ float bf2f(unsigned short h) {
    return __uint_as_float(((unsigned int)h) << 16);
}

// ws layout (bytes)
#define PMW_OFF   0u        // [4*64*64] bf16
#define THW_OFF   32768u    // [256*512] bf16
#define PHW_OFF   294912u   // [256*512] bf16
#define GW_OFF    557056u   // [256*512] bf16
#define OUTW_OFF  819200u   // [512*256] bf16 (scaled by BN inv)
#define OUTB_OFF  1081344u  // [512] f32 (folded BN bias)
#define WS_BYTES  1083392u

__global__ void prep_kernel(const float* __restrict__ pm_w, const float* __restrict__ g_w,
                            const float* __restrict__ th_w, const float* __restrict__ ph_w,
                            const float* __restrict__ out_w, const float* __restrict__ gamma,
                            const float* __restrict__ beta, const float* __restrict__ mean,
                            const float* __restrict__ var, char* __restrict__ ws) {
    int i = blockIdx.x * 256 + threadIdx.x;
    unsigned short* pmw = (unsigned short*)(ws + PMW_OFF);
    unsigned short* thw = (unsigned short*)(ws + THW_OFF);
    unsigned short* phw = (unsigned short*)(ws + PHW_OFF);
    unsigned short* gww = (unsigned short*)(ws + GW_OFF);
    unsigned short* oww = (unsigned short*)(ws + OUTW_OFF);
    float* ob = (float*)(ws + OUTB_OFF);
    if (i < 16384) pmw[i] = f2bf(pm_w[i]);
    if (i < 131072) {
        thw[i] = f2bf(th_w[i]);
        phw[i] = f2bf(ph_w[i]);
        gww[i] = f2bf(g_w[i]);
        int o = i >> 8;
        float inv = gamma[o] * rsqrtf(var[o] + 1e-5f);
        oww[i] = f2bf(out_w[i] * inv);
    }
    if (i < 512) {
        float inv = gamma[i] * rsqrtf(var[i] + 1e-5f);
        ob[i] = beta[i] - mean[i] * inv;
    }
}

// Fused per-batch kernel. 512 threads (8 waves), 160KB dynamic LDS, 1 block/CU.
// LDS overlays:
//   R1 (64K): q^T[64][512] -> ctx'^T[64][512] -> P[4][64][64](32K) + Y^T[64][256](32K)
//   R2 (64K): raw ctx[512][64] -> Phi^T[64][256](32K) + G[256][64](32K)
//   R3 (32K): Theta^T[64][256]
// All LDS tiles XOR-swizzled: byte = row*RB + ((2*col) ^ ((row&7)<<4))
__global__ __launch_bounds__(512, 2)
void lawin_main(const float* __restrict__ query, const float* __restrict__ context,
                const float* __restrict__ pm_b, const float* __restrict__ g_b,
                const float* __restrict__ th_b, const float* __restrict__ ph_b,
                const char* __restrict__ ws, float* __restrict__ out) {
    extern __shared__ char smem[];
    char* R1 = smem;
    char* R2 = smem + 65536;
    char* R3 = smem + 131072;

    const char* pmw = ws + PMW_OFF;
    const char* thw = ws + THW_OFF;
    const char* phw = ws + PHW_OFF;
    const char* gww = ws + GW_OFF;
    const char* oww = ws + OUTW_OFF;
    const float* ob = (const float*)(ws + OUTB_OFF);

    const int b = blockIdx.x;
    const int tid = threadIdx.x;
    const int wid = tid >> 6;
    const int lane = tid & 63;
    const int llo = lane & 15;
    const int lhi = lane >> 4;

    const float* qb = query + (size_t)b * (CIN * NTOK);
    const float* cb = context + (size_t)b * (CIN * NTOK);
    float* outb = out + (size_t)b * (CIN * NTOK);

    // ---------- load: q -> R1 as q^T (bf16, swizzled); ctx -> R2 raw [512][64] ----------
    #pragma unroll
    for (int it = 0; it < 16; ++it) {
        int idx = it * 512 + tid;          // float4 index into [512][64]
        int ch = idx >> 4;
        int t0 = (idx & 15) * 4;
        f32x4 qv = *(const f32x4*)(qb + idx * 4);
        f32x4 cv = *(const f32x4*)(cb + idx * 4);
        #pragma unroll
        for (int j = 0; j < 4; ++j) {
            int t = t0 + j;
            *(unsigned short*)(R1 + t * 1024 + ((ch * 2) ^ ((t & 7) << 4))) = f2bf(qv[j]);
        }
        us4 cp;
        cp[0] = f2bf(cv[0]); cp[1] = f2bf(cv[1]); cp[2] = f2bf(cv[2]); cp[3] = f2bf(cv[3]);
        *(us4*)(R2 + ch * 128 + ((t0 * 2) ^ ((ch & 7) << 4))) = cp;
    }
    __syncthreads();

    // ---------- stage 1: Theta^T[64][256] = q^T @ th_w^T  (per wave: 32 d-cols) ----------
    {
        const int dbase = wid * 32;
        f32x4 acc[4][2] = {};
        #pragma unroll 4
        for (int ks = 0; ks < 16; ++ks) {
            const int kb = ks * 64 + lhi * 16;
            short8 a[4], bb[2];
            #pragma unroll
            for (int tr = 0; tr < 4; ++tr) {
                int row = tr * 16 + llo;
                a[tr] = *(const short8*)(R1 + row * 1024 + (kb ^ ((row & 7) << 4)));
            }
            #pragma unroll
            for (int i = 0; i < 2; ++i) {
                int d = dbase + i * 16 + llo;
                bb[i] = *(const short8*)(thw + d * 1024 + kb);
            }
            #pragma unroll
            for (int tr = 0; tr < 4; ++tr)
                #pragma unroll
                for (int i = 0; i < 2; ++i)
                    acc[tr][i] = __builtin_amdgcn_mfma_f32_16x16x32_bf16(a[tr], bb[i], acc[tr][i], 0, 0, 0);
        }
        #pragma unroll
        for (int i = 0; i < 2; ++i) {
            const int d = dbase + i * 16 + llo;
            const float bias = th_b[d];
            #pragma unroll
            for (int tr = 0; tr < 4; ++tr)
                #pragma unroll
                for (int r = 0; r < 4; ++r) {
                    int tok = tr * 16 + lhi * 4 + r;
                    *(unsigned short*)(R3 + tok * 512 + ((d * 2) ^ ((tok & 7) << 4))) = f2bf(acc[tr][i][r] + bias);
                }
        }
    }
    __syncthreads();

    // ---------- stage 2: posmix: ctx' = ctx + ctx_h @ pm_w^T + pm_b; write ctx'^T to R1 ----------
    {
        const int h = wid >> 1;
        const int cbase = wid * 64;
        f32x4 acc[4][4] = {};
        #pragma unroll
        for (int ks = 0; ks < 2; ++ks) {
            const int kb = ks * 64 + lhi * 16;
            short8 a[4], bb[4];
            #pragma unroll
            for (int cr = 0; cr < 4; ++cr) {
                int c = cbase + cr * 16 + llo;
                a[cr] = *(const short8*)(R2 + c * 128 + (kb ^ ((c & 7) << 4)));
            }
            #pragma unroll
            for (int mt = 0; mt < 4; ++mt) {
                int m = mt * 16 + llo;
                bb[mt] = *(const short8*)(pmw + (h * 64 + m) * 128 + kb);
            }
            #pragma unroll
            for (int cr = 0; cr < 4; ++cr)
                #pragma unroll
                for (int mt = 0; mt < 4; ++mt)
                    acc[cr][mt] = __builtin_amdgcn_mfma_f32_16x16x32_bf16(a[cr], bb[mt], acc[cr][mt], 0, 0, 0);
        }
        #pragma unroll
        for (int mt = 0; mt < 4; ++mt) {
            const int m = mt * 16 + llo;
            const float pb = pm_b[h * 64 + m];
            #pragma unroll
            for (int cr = 0; cr < 4; ++cr) {
                const int c0 = cbase + cr * 16 + lhi * 4;
                us4 pk;
                #pragma unroll
                for (int r = 0; r < 4; ++r) {
                    int c = c0 + r;
                    float resid = bf2f(*(const unsigned short*)(R2 + c * 128 + ((m * 2) ^ ((c & 7) << 4))));
                    pk[r] = f2bf(acc[cr][mt][r] + pb + resid);
                }
                *(us4*)(R1 + m * 1024 + ((c0 * 2) ^ ((m & 7) << 4))) = pk;
            }
        }
    }
    __syncthreads();

    // ---------- stage 3: waves 0-3: Phi^T[64][256] -> R2a ; waves 4-7: G[256][64] -> R2b ----------
    if (wid < 4) {
        const int dbase = wid * 64;
        f32x4 acc[4][4] = {};
        #pragma unroll 4
        for (int ks = 0; ks < 16; ++ks) {
            const int kb = ks * 64 + lhi * 16;
            short8 a[4], bb[4];
            #pragma unroll
            for (int tr = 0; tr < 4; ++tr) {
                int row = tr * 16 + llo;
                a[tr] = *(const short8*)(R1 + row * 1024 + (kb ^ ((row & 7) << 4)));
            }
            #pragma unroll
            for (int i = 0; i < 4; ++i) {
                int d = dbase + i * 16 + llo;
                bb[i] = *(const short8*)(phw + d * 1024 + kb);
            }
            #pragma unroll
            for (int tr = 0; tr < 4; ++tr)
                #pragma unroll
                for (int i = 0; i < 4; ++i)
                    acc[tr][i] = __builtin_amdgcn_mfma_f32_16x16x32_bf16(a[tr], bb[i], acc[tr][i], 0, 0, 0);
        }
        #pragma unroll
        for (int i = 0; i < 4; ++i) {
            const int d = dbase + i * 16 + llo;
            const float bias = ph_b[d];
            #pragma unroll
            for (int tr = 0; tr < 4; ++tr)
                #pragma unroll
                for (int r = 0; r < 4; ++r) {
                    int tok = tr * 16 + lhi * 4 + r;
                    *(unsigned short*)(R2 + tok * 512 + ((d * 2) ^ ((tok & 7) << 4))) = f2bf(acc[tr][i][r] + bias);
                }
        }
    } else {
        const int dbase = (wid - 4) * 64;
        f32x4 acc[4][4] = {};   // [dr][mt]
        #pragma unroll 4
        for (int ks = 0; ks < 16; ++ks) {
            const int kb = ks * 64 + lhi * 16;
            short8 a[4], bb[4];
            #pragma unroll
            for (int dr = 0; dr < 4; ++dr) {
                int d = dbase + dr * 16 + llo;
                a[dr] = *(const short8*)(gww + d * 1024 + kb);
            }
            #pragma unroll
            for (int mt = 0; mt < 4; ++mt) {
                int m = mt * 16 + llo;
                bb[mt] = *(const short8*)(R1 + m * 1024 + (kb ^ ((m & 7) << 4)));
            }
            #pragma unroll
            for (int dr = 0; dr < 4; ++dr)
                #pragma unroll
                for (int mt = 0; mt < 4; ++mt)
                    acc[dr][mt] = __builtin_amdgcn_mfma_f32_16x16x32_bf16(a[dr], bb[mt], acc[dr][mt], 0, 0, 0);
        }
        #pragma unroll
        for (int mt = 0; mt < 4; ++mt) {
            const int m = mt * 16 + llo;
            #pragma unroll
            for (int dr = 0; dr < 4; ++dr)
                #pragma unroll
                for (int r = 0; r < 4; ++r) {
                    int d = dbase + dr * 16 + lhi * 4 + r;
                    *(unsigned short*)(R2 + 32768 + d * 128 + ((m * 2) ^ ((d & 7) << 4))) = f2bf(acc[dr][mt][r] + g_b[d]);
                }
        }
    }
    __syncthreads();

    // ---------- stage 4: S = Theta^T_h @ Phi_h /8, softmax rows, P bf16 -> R1a ----------
    {
        const int h = wid >> 1;
        const int nqb = (wid & 1) * 32;
        f32x4 acc[2][4] = {};
        #pragma unroll
        for (int ks = 0; ks < 2; ++ks) {
            const int kb = h * 128 + ks * 64 + lhi * 16;
            short8 a[2], bb[4];
            #pragma unroll
            for (int tr = 0; tr < 2; ++tr) {
                int nq = nqb + tr * 16 + llo;
                a[tr] = *(const short8*)(R3 + nq * 512 + (kb ^ ((nq & 7) << 4)));
            }
            #pragma unroll
            for (int ct = 0; ct < 4; ++ct) {
                int nc = ct * 16 + llo;
                bb[ct] = *(const short8*)(R2 + nc * 512 + (kb ^ ((nc & 7) << 4)));
            }
            #pragma unroll
            for (int tr = 0; tr < 2; ++tr)
                #pragma unroll
                for (int ct = 0; ct < 4; ++ct)
                    acc[tr][ct] = __builtin_amdgcn_mfma_f32_16x16x32_bf16(a[tr], bb[ct], acc[tr][ct], 0, 0, 0);
        }
        #pragma unroll
        for (int tr = 0; tr < 2; ++tr) {
            #pragma unroll
            for (int r = 0; r < 4; ++r) {
                float l0 = acc[tr][0][r] * 0.125f;
                float l1 = acc[tr][1][r] * 0.125f;
                float l2 = acc[tr][2][r] * 0.125f;
                float l3 = acc[tr][3][r] * 0.125f;
                float mx = fmaxf(fmaxf(l0, l1), fmaxf(l2, l3));
                mx = fmaxf(mx, __shfl_xor(mx, 1));
                mx = fmaxf(mx, __shfl_xor(mx, 2));
                mx = fmaxf(mx, __shfl_xor(mx, 4));
                mx = fmaxf(mx, __shfl_xor(mx, 8));
                float e0 = __expf(l0 - mx);
                float e1 = __expf(l1 - mx);
                float e2 = __expf(l2 - mx);
                float e3 = __expf(l3 - mx);
                float s = e0 + e1 + e2 + e3;
                s += __shfl_xor(s, 1);
                s += __shfl_xor(s, 2);
                s += __shfl_xor(s, 4);
                s += __shfl_xor(s, 8);
                float rinv = 1.0f / s;
                int nq = nqb + tr * 16 + lhi * 4 + r;
                char* pl = R1 + h * 8192 + nq * 128;
                int sw = (nq & 7) << 4;
                *(unsigned short*)(pl + ((2 * llo) ^ sw))        = f2bf(e0 * rinv);
                *(unsigned short*)(pl + ((2 * (16 + llo)) ^ sw)) = f2bf(e1 * rinv);
                *(unsigned short*)(pl + ((2 * (32 + llo)) ^ sw)) = f2bf(e2 * rinv);
                *(unsigned short*)(pl + ((2 * (48 + llo)) ^ sw)) = f2bf(e3 * rinv);
            }
        }
    }
    __syncthreads();

    // ---------- stage 5: Y^T[64][256] = P_h @ G_h^T  -> R1b ----------
    {
        const int h = wid >> 1;
        const int db = (wid & 1) * 32;
        f32x4 acc[4][2] = {};
        #pragma unroll
        for (int ks = 0; ks < 2; ++ks) {
            const int kb = ks * 64 + lhi * 16;
            short8 a[4], bb[2];
            #pragma unroll
            for (int tr = 0; tr < 4; ++tr) {
                int nq = tr * 16 + llo;
                a[tr] = *(const short8*)(R1 + h * 8192 + nq * 128 + (kb ^ ((nq & 7) << 4)));
            }
            #pragma unroll
            for (int i = 0; i < 2; ++i) {
                int dg = h * 64 + db + i * 16 + llo;
                bb[i] = *(const short8*)(R2 + 32768 + dg * 128 + (kb ^ ((dg & 7) << 4)));
            }
            #pragma unroll
            for (int tr = 0; tr < 4; ++tr)
                #pragma unroll
                for (int i = 0; i < 2; ++i)
                    acc[tr][i] = __builtin_amdgcn_mfma_f32_16x16x32_bf16(a[tr], bb[i], acc[tr][i], 0, 0, 0);
        }
        #pragma unroll
        for (int i = 0; i < 2; ++i) {
            int dg = h * 64 + db + i * 16 + llo;
            #pragma unroll
            for (int tr = 0; tr < 4; ++tr)
                #pragma unroll
                for (int r = 0; r < 4; ++r) {
                    int nq = tr * 16 + lhi * 4 + r;
                    *(unsigned short*)(R1 + 32768 + nq * 512 + ((dg * 2) ^ ((nq & 7) << 4))) = f2bf(acc[tr][i][r]);
                }
        }
    }
    __syncthreads();

    // ---------- stage 6: Out^T = Y^T @ out_w^T (BN-folded) + bias + query residual ----------
    {
        const int obase = wid * 64;
        f32x4 acc[4][4] = {};
        #pragma unroll 2
        for (int ks = 0; ks < 8; ++ks) {
            const int kb = ks * 64 + lhi * 16;
            short8 a[4], bb[4];
            #pragma unroll
            for (int tr = 0; tr < 4; ++tr) {
                int tok = tr * 16 + llo;
                a[tr] = *(const short8*)(R1 + 32768 + tok * 512 + (kb ^ ((tok & 7) << 4)));
            }
            #pragma unroll
            for (int oc = 0; oc < 4; ++oc) {
                int o = obase + oc * 16 + llo;
                bb[oc] = *(const short8*)(oww + o * 512 + kb);
            }
            #pragma unroll
            for (int tr = 0; tr < 4; ++tr)
                #pragma unroll
                for (int oc = 0; oc < 4; ++oc)
                    acc[tr][oc] = __builtin_amdgcn_mfma_f32_16x16x32_bf16(a[tr], bb[oc], acc[tr][oc], 0, 0, 0);
        }
        #pragma unroll
        for (int oc = 0; oc < 4; ++oc) {
            const int o = obase + oc * 16 + llo;
            const float bias = ob[o];
            #pragma unroll
            for (int tr = 0; tr < 4; ++tr) {
                const int t0 = tr * 16 + lhi * 4;
                f32x4 qv = *(const f32x4*)(qb + o * 64 + t0);
                f32x4 ov;
                #pragma unroll
                for (int r = 0; r < 4; ++r) ov[r] = acc[tr][oc][r] + bias + qv[r];
                *(f32x4*)(outb + o * 64 + t0) = ov;
            }
        }
    }
}

extern "C" void kernel_launch(void* const* d_in, const int* in_sizes, int n_in,
                              void* d_out, int out_size, void* d_ws, size_t ws_size,
                              hipStream_t stream) {
    const float* query   = (const float*)d_in[0];
    const float* context = (const float*)d_in[1];
    const float* pm_w    = (const float*)d_in[2];
    const float* pm_b    = (const float*)d_in[3];
    const float* g_w     = (const float*)d_in[4];
    const float* g_b     = (const float*)d_in[5];
    const float* th_w    = (const float*)d_in[6];
    const float* th_b    = (const float*)d_in[7];
    const float* ph_w    = (const float*)d_in[8];
    const float* ph_b    = (const float*)d_in[9];
    const float* out_w   = (const float*)d_in[10];
    const float* gamma   = (const float*)d_in[11];
    const float* beta    = (const float*)d_in[12];
    const float* mean    = (const float*)d_in[13];
    const float* var     = (const float*)d_in[14];
    char* ws = (char*)d_ws;
    float* out = (float*)d_out;

    if (ws_size < WS_BYTES) return;

    prep_kernel<<<512, 256, 0, stream>>>(pm_w, g_w, th_w, ph_w, out_w, gamma, beta, mean, var, ws);

    hipFuncSetAttribute((const void*)lawin_main, hipFuncAttributeMaxDynamicSharedMemorySize, 163840);
    lawin_main<<<NBATCH, 512, 163840, stream>>>(query, context, pm_b, g_b, th_b, ph_b, ws, out);
}